// Round 14
// baseline (102.295 us; speedup 1.0000x reference)
//
#include <hip/hip_runtime.h>

// ResidualVQ forward: out[n] = codebook[argmin_k(-2 x.c_k + ||c_k||^2)]
// v14 = v13 pipeline (unchanged, correct) + 4 ABLATION DISPATCHES that
// isolate K-loop components; rocprof per-dispatch dur_us = component cost.
// ab_loadonly : fragment loads only            (load path wall?)
// ab_mfmaonly : MFMA chains only               (MFMA latency wall?)
// ab_noload   : MFMA + epilogue, no loads      (epilogue wall?)
// ab_noepi    : loads + MFMA, no epilogue      (prefetch interaction?)

typedef short bfrag __attribute__((ext_vector_type(8)));  // 8 bf16 = 4 VGPR
typedef float f32x4 __attribute__((ext_vector_type(4)));

constexpr int D = 128;
constexpr int BR = 32;      // rows per block -> grid 1024 = 4 blocks/CU
constexpr int NTH = 256;    // 4 waves
constexpr int LCAP = 1024;
#define MARGIN 3.25f

__device__ __forceinline__ unsigned fenc(float f) {
    unsigned u = __float_as_uint(f);
    return (u & 0x80000000u) ? ~u : (u | 0x80000000u);
}
__device__ __forceinline__ unsigned cvtpk(float a, float b) {
    unsigned r;
    asm("v_cvt_pk_bf16_f32 %0, %1, %2" : "=v"(r) : "v"(a), "v"(b));
    return r;
}
union FU { bfrag v; unsigned u[4]; };

__device__ __forceinline__ void conv8(const float* f, bfrag& hi, bfrag& lo) {
    FU h, l;
#pragma unroll
    for (int m = 0; m < 4; ++m) {
        float a = f[2 * m], b = f[2 * m + 1];
        unsigned hp = cvtpk(a, b);
        float ra = a - __uint_as_float(hp << 16);
        float rb = b - __uint_as_float(hp & 0xFFFF0000u);
        h.u[m] = hp;
        l.u[m] = cvtpk(ra, rb);
    }
    hi = h.v;
    lo = l.v;
}

#define MFMA(A, B, C) __builtin_amdgcn_mfma_f32_16x16x32_bf16(A, B, C, 0, 0, 0)

// --- prep: exact cnorm + bf16 fragment cast (verbatim v13) ---
__global__ __launch_bounds__(256) void prep_kernel(const float* __restrict__ cb,
                                                   float* __restrict__ cnorm,
                                                   short* __restrict__ hi, int K) {
    const int tg = blockIdx.x * 256 + threadIdx.x;
    {
        const int cg = tg >> 8;
        const int r = tg & 255;
        const int ks = r >> 6;
        const int lane = r & 63;
        const int kg = lane >> 4, la = lane & 15;
        const float* src = cb + (size_t)(cg * 16 + la) * D + ks * 32 + kg * 8;
        float4 f0 = *(const float4*)src;
        float4 f1 = *(const float4*)(src + 4);
        FU h;
        h.u[0] = cvtpk(f0.x, f0.y);
        h.u[1] = cvtpk(f0.z, f0.w);
        h.u[2] = cvtpk(f1.x, f1.y);
        h.u[3] = cvtpk(f1.z, f1.w);
        ((bfrag*)hi)[tg] = h.v;
    }
    if (tg < K) {
        const float4* c = (const float4*)(cb + (size_t)tg * D);
        float s0 = 0.f, s1 = 0.f, s2 = 0.f, s3 = 0.f;
#pragma unroll
        for (int i = 0; i < D / 4; ++i) {
            float4 v = c[i];
            s0 = fmaf(v.x, v.x, s0);
            s1 = fmaf(v.y, v.y, s1);
            s2 = fmaf(v.z, v.z, s2);
            s3 = fmaf(v.w, v.w, s3);
        }
        cnorm[tg] = (s0 + s1) + (s2 + s3);
    }
}

// --- main kernel: verbatim v13 (stagger version; 45.5 us, passes) ---
__global__ __launch_bounds__(NTH, 4) void vq_mfma(const float* __restrict__ x,
                                                  const float* __restrict__ cb,
                                                  const short* __restrict__ cbh,
                                                  const float* __restrict__ cnorm,
                                                  float* __restrict__ out,
                                                  int N, int K) {
    __shared__ float cns[1024];
    __shared__ unsigned clist[LCAP];
    __shared__ unsigned long long win[BR];
    __shared__ int ccnt;

    const int tid = threadIdx.x;
    const int lane = tid & 63;
    const int wv = tid >> 6;
    const int rg = wv >> 1;
    const int khw = wv & 1;
    const int la = lane & 15;
    const int kg = lane >> 4;
    const int row0 = blockIdx.x * BR;
    const int phase = (int)((blockIdx.x * 0x9E3779B1u) >> 24) & 15;

    if (tid < BR) win[tid] = ~0ull;
    if (tid == 0) ccnt = 0;
    for (int i = tid; i < K; i += NTH) cns[i] = cnorm[i];

    bfrag xh[4], xl[4];
    {
        const int xrow = row0 + rg * 16 + la;
        const float* xp = x + (size_t)xrow * D + kg * 8;
#pragma unroll
        for (int ks = 0; ks < 4; ++ks) {
            float4 f0 = *(const float4*)(xp + ks * 32);
            float4 f1 = *(const float4*)(xp + ks * 32 + 4);
            float v[8] = {-2.f * f0.x, -2.f * f0.y, -2.f * f0.z, -2.f * f0.w,
                          -2.f * f1.x, -2.f * f1.y, -2.f * f1.z, -2.f * f1.w};
            conv8(v, xh[ks], xl[ks]);
        }
    }
    __syncthreads();

    const bfrag* fpb = (const bfrag*)cbh + (size_t)khw * 8192 + lane;
    const int row = rg * 16 + la;
    float rm = 3.4e38f;

    auto load8 = [&](bfrag* dst, int tp) {
        const bfrag* p = fpb + tp * 512;
#pragma unroll
        for (int cf = 0; cf < 2; ++cf)
#pragma unroll
            for (int ks = 0; ks < 4; ++ks)
                dst[cf * 4 + ks] = p[cf * 256 + ks * 64];
    };

    auto compute = [&](const bfrag* f, int tp) {
        const int cbase = khw * 512 + tp * 32;
        f32x4 acc[2];
        acc[0] = *(const f32x4*)&cns[cbase + kg * 4];
        acc[1] = *(const f32x4*)&cns[cbase + 16 + kg * 4];
#pragma unroll
        for (int ks = 0; ks < 4; ++ks)
#pragma unroll
            for (int cf = 0; cf < 2; ++cf) {
                acc[cf] = MFMA(f[cf * 4 + ks], xh[ks], acc[cf]);
                acc[cf] = MFMA(f[cf * 4 + ks], xl[ks], acc[cf]);
            }
        float m = fminf(fminf(fminf(acc[0][0], acc[0][1]), fminf(acc[0][2], acc[0][3])),
                        fminf(fminf(acc[1][0], acc[1][1]), fminf(acc[1][2], acc[1][3])));
        m = fminf(m, __shfl_xor(m, 16));
        m = fminf(m, __shfl_xor(m, 32));
        if (__any(m < rm + MARGIN)) {
            const float thr = fminf(rm, m) + MARGIN;
#pragma unroll
            for (int cf = 0; cf < 2; ++cf)
#pragma unroll
                for (int i = 0; i < 4; ++i) {
                    if (acc[cf][i] < thr) {
                        int p = atomicAdd(&ccnt, 1);
                        if (p < LCAP)
                            clist[p] = (unsigned)((row << 10)
                                                  | (cbase + cf * 16 + kg * 4 + i));
                    }
                }
        }
        rm = fminf(rm, m);
    };

    bfrag cur[8], nxt[8];
    load8(cur, phase);
#pragma unroll 1
    for (int t = 0; t < 16; t += 2) {
        load8(nxt, (t + 1 + phase) & 15);
        compute(cur, (t + phase) & 15);
        if (t + 2 < 16) load8(cur, (t + 2 + phase) & 15);
        compute(nxt, (t + 1 + phase) & 15);
    }

    __syncthreads();

    const int nc = (ccnt > LCAP) ? LCAP : ccnt;
    for (int b = wv * 4 + kg; b < nc; b += 16) {
        const unsigned e = clist[b];
        const int crow = e >> 10, code = e & 1023;
        const float4* xr4 = (const float4*)(x + (size_t)(row0 + crow) * D + la * 8);
        const float4* cr4 = (const float4*)(cb + (size_t)code * D + la * 8);
        float4 a0 = xr4[0], a1 = xr4[1], b0 = cr4[0], b1 = cr4[1];
        float s = a0.x * b0.x;
        s = fmaf(a0.y, b0.y, s); s = fmaf(a0.z, b0.z, s); s = fmaf(a0.w, b0.w, s);
        s = fmaf(a1.x, b1.x, s); s = fmaf(a1.y, b1.y, s);
        s = fmaf(a1.z, b1.z, s); s = fmaf(a1.w, b1.w, s);
#pragma unroll
        for (int off = 1; off <= 8; off <<= 1) s += __shfl_xor(s, off);
        const float dist = fmaf(-2.f, s, cns[code]);
        if (la == 0)
            atomicMin(&win[crow],
                      ((unsigned long long)fenc(dist) << 32) | (unsigned)code);
    }
    __syncthreads();

    {
        const int r = tid >> 3, q = tid & 7;
        const int idx = (int)(win[r] & 0xFFFFFFFFull);
        const float4* cs = (const float4*)(cb + (size_t)idx * D + q * 16);
        float4* od = (float4*)(out + (size_t)(row0 + r) * D + q * 16);
#pragma unroll
        for (int i = 0; i < 4; ++i) od[i] = cs[i];
    }
}

// ================= ABLATION KERNELS (diagnostic dispatches) =================
// benign bf16 init ~1.0 (exponent sane, lane-dependent mantissa bits)
__device__ __forceinline__ void fake_frag(bfrag& f, int lane, int salt) {
    FU u;
#pragma unroll
    for (int m = 0; m < 4; ++m)
        u.u[m] = (0x3F803F80u | ((lane & 7) << 1) | ((salt & 7) << 17));
    f = u.v;
}

// A) loads only — same addressing/double-buffer as vq_mfma's K-loop
__global__ __launch_bounds__(NTH, 4) void ab_loadonly(const short* __restrict__ cbh,
                                                      unsigned* __restrict__ sink) {
    const int tid = threadIdx.x, lane = tid & 63, wv = tid >> 6, khw = wv & 1;
    const bfrag* fpb = (const bfrag*)cbh + (size_t)khw * 8192 + lane;
    FU cur[8], nxt[8];
    unsigned acc = 0;
    auto load8 = [&](FU* dst, int tp) {
        const bfrag* p = fpb + tp * 512;
#pragma unroll
        for (int cf = 0; cf < 2; ++cf)
#pragma unroll
            for (int ks = 0; ks < 4; ++ks)
                dst[cf * 4 + ks].v = p[cf * 256 + ks * 64];
    };
    auto use8 = [&](const FU* f) {
#pragma unroll
        for (int i = 0; i < 8; ++i)
            acc ^= f[i].u[0] ^ f[i].u[1] ^ f[i].u[2] ^ f[i].u[3];
    };
    load8(cur, 0);
#pragma unroll 1
    for (int t = 0; t < 16; t += 2) {
        load8(nxt, (t + 1) & 15);
        use8(cur);
        if (t + 2 < 16) load8(cur, (t + 2) & 15);
        use8(nxt);
    }
    asm volatile("" :: "v"(acc));
    if (lane == 0) sink[blockIdx.x * 4 + wv] = acc;
}

// B) MFMA only — v11's exact chain shape (2 chains x depth 8 per tile), no memory
__global__ __launch_bounds__(NTH, 4) void ab_mfmaonly(float* __restrict__ sink) {
    const int tid = threadIdx.x, lane = tid & 63, wv = tid >> 6;
    bfrag xh[4], xl[4], f[8];
#pragma unroll
    for (int ks = 0; ks < 4; ++ks) { fake_frag(xh[ks], lane, ks); fake_frag(xl[ks], lane, ks + 4); }
#pragma unroll
    for (int i = 0; i < 8; ++i) fake_frag(f[i], lane, i);
    f32x4 vs0 = {0.f, 0.f, 0.f, 0.f}, vs1 = {0.f, 0.f, 0.f, 0.f};
#pragma unroll 1
    for (int t = 0; t < 16; ++t) {
        f32x4 a0 = {0.f, 0.f, 0.f, 0.f}, a1 = {0.f, 0.f, 0.f, 0.f};
#pragma unroll
        for (int ks = 0; ks < 4; ++ks) {
            a0 = MFMA(f[ks], xh[ks], a0); a0 = MFMA(f[ks], xl[ks], a0);
            a1 = MFMA(f[4 + ks], xh[ks], a1); a1 = MFMA(f[4 + ks], xl[ks], a1);
        }
        vs0 += a0; vs1 += a1;
    }
    float r = vs0[0] + vs0[1] + vs0[2] + vs0[3] + vs1[0] + vs1[1] + vs1[2] + vs1[3];
    asm volatile("" :: "v"(r));
    if (lane == 0) sink[blockIdx.x * 4 + wv] = r;
}

// C) MFMA + epilogue (fmin tree, 2 shfl, rm, predicated count), no loads
__global__ __launch_bounds__(NTH, 4) void ab_noload(float* __restrict__ sink) {
    const int tid = threadIdx.x, lane = tid & 63, wv = tid >> 6;
    bfrag xh[4], xl[4], f[8];
#pragma unroll
    for (int ks = 0; ks < 4; ++ks) { fake_frag(xh[ks], lane, ks); fake_frag(xl[ks], lane, ks + 4); }
#pragma unroll
    for (int i = 0; i < 8; ++i) fake_frag(f[i], lane, i);
    float rm = 3.4e38f;
    int cnt = 0;
#pragma unroll 1
    for (int t = 0; t < 16; ++t) {
        f32x4 a0 = {0.f, 0.f, 0.f, 0.f}, a1 = {0.f, 0.f, 0.f, 0.f};
#pragma unroll
        for (int ks = 0; ks < 4; ++ks) {
            a0 = MFMA(f[ks], xh[ks], a0); a0 = MFMA(f[ks], xl[ks], a0);
            a1 = MFMA(f[4 + ks], xh[ks], a1); a1 = MFMA(f[4 + ks], xl[ks], a1);
        }
        a0 += f32x4{(float)t, 0.f, 0.f, 0.f};  // vary per tile
        float m = fminf(fminf(fminf(a0[0], a0[1]), fminf(a0[2], a0[3])),
                        fminf(fminf(a1[0], a1[1]), fminf(a1[2], a1[3])));
        m = fminf(m, __shfl_xor(m, 16));
        m = fminf(m, __shfl_xor(m, 32));
        if (__any(m < rm + MARGIN)) {
            const float thr = fminf(rm, m) + MARGIN;
#pragma unroll
            for (int i = 0; i < 4; ++i) cnt += (a0[i] < thr) + (a1[i] < thr);
        }
        rm = fminf(rm, m);
    }
    float r = rm + (float)cnt;
    asm volatile("" :: "v"(r));
    if (lane == 0) sink[blockIdx.x * 4 + wv] = r;
}

// D) loads + MFMA (exact v11 double-buffer), no epilogue
__global__ __launch_bounds__(NTH, 4) void ab_noepi(const short* __restrict__ cbh,
                                                   float* __restrict__ sink) {
    const int tid = threadIdx.x, lane = tid & 63, wv = tid >> 6, khw = wv & 1;
    const bfrag* fpb = (const bfrag*)cbh + (size_t)khw * 8192 + lane;
    bfrag xh[4], xl[4];
#pragma unroll
    for (int ks = 0; ks < 4; ++ks) { fake_frag(xh[ks], lane, ks); fake_frag(xl[ks], lane, ks + 4); }
    f32x4 vs0 = {0.f, 0.f, 0.f, 0.f}, vs1 = {0.f, 0.f, 0.f, 0.f};
    bfrag cur[8], nxt[8];
    auto load8 = [&](bfrag* dst, int tp) {
        const bfrag* p = fpb + tp * 512;
#pragma unroll
        for (int cf = 0; cf < 2; ++cf)
#pragma unroll
            for (int ks = 0; ks < 4; ++ks)
                dst[cf * 4 + ks] = p[cf * 256 + ks * 64];
    };
    auto comp = [&](const bfrag* f) {
        f32x4 a0 = {0.f, 0.f, 0.f, 0.f}, a1 = {0.f, 0.f, 0.f, 0.f};
#pragma unroll
        for (int ks = 0; ks < 4; ++ks) {
            a0 = MFMA(f[ks], xh[ks], a0); a0 = MFMA(f[ks], xl[ks], a0);
            a1 = MFMA(f[4 + ks], xh[ks], a1); a1 = MFMA(f[4 + ks], xl[ks], a1);
        }
        vs0 += a0; vs1 += a1;
    };
    load8(cur, 0);
#pragma unroll 1
    for (int t = 0; t < 16; t += 2) {
        load8(nxt, (t + 1) & 15);
        comp(cur);
        if (t + 2 < 16) load8(cur, (t + 2) & 15);
        comp(nxt);
    }
    float r = vs0[0] + vs0[1] + vs0[2] + vs0[3] + vs1[0] + vs1[1] + vs1[2] + vs1[3];
    asm volatile("" :: "v"(r));
    if (lane == 0) sink[blockIdx.x * 4 + wv] = r;
}

extern "C" void kernel_launch(void* const* d_in, const int* in_sizes, int n_in,
                              void* d_out, int out_size, void* d_ws, size_t ws_size,
                              hipStream_t stream) {
    const float* x = (const float*)d_in[0];
    const float* cb = (const float*)d_in[1];
    float* out = (float*)d_out;
    const int N = in_sizes[0] / D;   // 32768
    const int K = in_sizes[1] / D;   // 1024

    float* cnorm = (float*)d_ws;                          // 4 KB
    short* cbh = (short*)((char*)d_ws + 4096);            // 256 KB
    char* sinks = (char*)d_ws + 4096 + 262144;            // 4 x 16 KB sinks

    hipLaunchKernelGGL(prep_kernel, dim3(K * 16 / 256), dim3(256), 0, stream,
                       cb, cnorm, cbh, K);
    hipLaunchKernelGGL(vq_mfma, dim3(N / BR), dim3(NTH), 0, stream,
                       x, cb, cbh, cnorm, out, N, K);
    // ---- diagnostics (separate dispatches; rocprof reports each dur_us) ----
    hipLaunchKernelGGL(ab_loadonly, dim3(N / BR), dim3(NTH), 0, stream,
                       cbh, (unsigned*)(sinks + 0 * 16384));
    hipLaunchKernelGGL(ab_mfmaonly, dim3(N / BR), dim3(NTH), 0, stream,
                       (float*)(sinks + 1 * 16384));
    hipLaunchKernelGGL(ab_noload, dim3(N / BR), dim3(NTH), 0, stream,
                       (float*)(sinks + 2 * 16384));
    hipLaunchKernelGGL(ab_noepi, dim3(N / BR), dim3(NTH), 0, stream,
                       cbh, (float*)(sinks + 3 * 16384));
}

// Round 15
// 49.672 us; speedup vs baseline: 2.0594x; 2.0594x over previous
//
#include <hip/hip_runtime.h>

// ResidualVQ forward: out[n] = codebook[argmin_k(-2 x.c_k + ||c_k||^2)]
// v15 = v13 (minus null stagger) + amdgpu_waves_per_eu(4,4).
// Round-14 ablations: every component individually fast (sum ~52us, each
// <=~20us) yet full kernel = 45us => serial sum, no overlap. Cause:
// VGPR_Count=64 (compiler squeezed for 8 waves/EU) cannot hold the double
// buffer (needs ~118) -> loads sunk to just-before-use -> serial tiles.
// Fix: pin the allocator at 4 waves/EU (128 VGPR budget) so the register
// double-buffer is real and tile t+1 loads fly under tile t compute.

typedef short bfrag __attribute__((ext_vector_type(8)));  // 8 bf16 = 4 VGPR
typedef float f32x4 __attribute__((ext_vector_type(4)));

constexpr int D = 128;      // embedding dim
constexpr int BR = 32;      // rows per block -> grid 1024 = 4 blocks/CU
constexpr int NTH = 256;    // 4 waves: 2 row-groups (16 rows) x 2 K-halves
constexpr int LCAP = 1024;  // candidate capacity per block
#define MARGIN 3.25f        // > 2 * max |approx dist err| (x split; cb bf16)

__device__ __forceinline__ unsigned fenc(float f) {  // order-preserving f32->u32
    unsigned u = __float_as_uint(f);
    return (u & 0x80000000u) ? ~u : (u | 0x80000000u);
}
__device__ __forceinline__ unsigned cvtpk(float a, float b) {
    unsigned r;
    asm("v_cvt_pk_bf16_f32 %0, %1, %2" : "=v"(r) : "v"(a), "v"(b));
    return r;
}
union FU { bfrag v; unsigned u[4]; };

// 8 fp32 -> bf16 hi fragment + bf16 lo (residual) fragment
__device__ __forceinline__ void conv8(const float* f, bfrag& hi, bfrag& lo) {
    FU h, l;
#pragma unroll
    for (int m = 0; m < 4; ++m) {
        float a = f[2 * m], b = f[2 * m + 1];
        unsigned hp = cvtpk(a, b);
        float ra = a - __uint_as_float(hp << 16);
        float rb = b - __uint_as_float(hp & 0xFFFF0000u);
        h.u[m] = hp;
        l.u[m] = cvtpk(ra, rb);
    }
    hi = h.v;
    lo = l.v;
}

// --- prep: exact cnorm (K threads) + bf16 fragment cast (K*16 threads) ---
__global__ __launch_bounds__(256) void prep_kernel(const float* __restrict__ cb,
                                                   float* __restrict__ cnorm,
                                                   short* __restrict__ hi, int K) {
    const int tg = blockIdx.x * 256 + threadIdx.x;  // 0..16383
    {
        const int cg = tg >> 8;
        const int r = tg & 255;
        const int ks = r >> 6;
        const int lane = r & 63;
        const int kg = lane >> 4, la = lane & 15;
        const float* src = cb + (size_t)(cg * 16 + la) * D + ks * 32 + kg * 8;
        float4 f0 = *(const float4*)src;
        float4 f1 = *(const float4*)(src + 4);
        FU h;
        h.u[0] = cvtpk(f0.x, f0.y);
        h.u[1] = cvtpk(f0.z, f0.w);
        h.u[2] = cvtpk(f1.x, f1.y);
        h.u[3] = cvtpk(f1.z, f1.w);
        ((bfrag*)hi)[tg] = h.v;
    }
    if (tg < K) {
        const float4* c = (const float4*)(cb + (size_t)tg * D);
        float s0 = 0.f, s1 = 0.f, s2 = 0.f, s3 = 0.f;
#pragma unroll
        for (int i = 0; i < D / 4; ++i) {
            float4 v = c[i];
            s0 = fmaf(v.x, v.x, s0);
            s1 = fmaf(v.y, v.y, s1);
            s2 = fmaf(v.z, v.z, s2);
            s3 = fmaf(v.w, v.w, s3);
        }
        cnorm[tg] = (s0 + s1) + (s2 + s3);
    }
}

__global__ __launch_bounds__(NTH)
__attribute__((amdgpu_waves_per_eu(4, 4)))  // pin allocator: 128-VGPR budget
void vq_mfma(const float* __restrict__ x,
             const float* __restrict__ cb,
             const short* __restrict__ cbh,
             const float* __restrict__ cnorm,
             float* __restrict__ out,
             int N, int K) {
    __shared__ float cns[1024];          // 4 KB
    __shared__ unsigned clist[LCAP];     // 4 KB
    __shared__ unsigned long long win[BR];
    __shared__ int ccnt;

    const int tid = threadIdx.x;
    const int lane = tid & 63;
    const int wv = tid >> 6;   // 0..3
    const int rg = wv >> 1;    // row-group (16 rows)
    const int khw = wv & 1;    // K half (512 codes) this wave covers
    const int la = lane & 15;
    const int kg = lane >> 4;
    const int row0 = blockIdx.x * BR;

    if (tid < BR) win[tid] = ~0ull;
    if (tid == 0) ccnt = 0;
    for (int i = tid; i < K; i += NTH) cns[i] = cnorm[i];

    // ---- (-2x) -> split-bf16 B-fragments in registers (col=la=row, k=kg*8+j) ----
    bfrag xh[4], xl[4];
    {
        const int xrow = row0 + rg * 16 + la;
        const float* xp = x + (size_t)xrow * D + kg * 8;
#pragma unroll
        for (int ks = 0; ks < 4; ++ks) {
            float4 f0 = *(const float4*)(xp + ks * 32);
            float4 f1 = *(const float4*)(xp + ks * 32 + 4);
            float v[8] = {-2.f * f0.x, -2.f * f0.y, -2.f * f0.z, -2.f * f0.w,
                          -2.f * f1.x, -2.f * f1.y, -2.f * f1.z, -2.f * f1.w};
            conv8(v, xh[ks], xl[ks]);
        }
    }
    __syncthreads();  // ccnt/win/cns ready before any appends

    // per-lane fragment pointer for this wave's K half (L2-resident, 256 KB)
    const bfrag* fpb = (const bfrag*)cbh + (size_t)khw * 8192 + lane;
    const int row = rg * 16 + la;  // block-local row this lane owns
    float rm = 3.4e38f;            // running approx row-min (register)

    auto load8 = [&](bfrag* dst, int tp) {  // tp = tile index
        const bfrag* p = fpb + tp * 512;
#pragma unroll
        for (int cf = 0; cf < 2; ++cf)
#pragma unroll
            for (int ks = 0; ks < 4; ++ks)
                dst[cf * 4 + ks] = p[cf * 256 + ks * 64];  // global_load_dwordx4
    };

    auto compute = [&](const bfrag* f, int tp) {  // one 32-code tile
        const int cbase = khw * 512 + tp * 32;
        f32x4 acc[2];
        acc[0] = *(const f32x4*)&cns[cbase + kg * 4];        // cn folded in
        acc[1] = *(const f32x4*)&cns[cbase + 16 + kg * 4];
#pragma unroll
        for (int ks = 0; ks < 4; ++ks)
#pragma unroll
            for (int cf = 0; cf < 2; ++cf) {
                // swapped operands: A=codebook, B=x -> C[row=code][col=x-row]
                acc[cf] = __builtin_amdgcn_mfma_f32_16x16x32_bf16(
                    f[cf * 4 + ks], xh[ks], acc[cf], 0, 0, 0);
                acc[cf] = __builtin_amdgcn_mfma_f32_16x16x32_bf16(
                    f[cf * 4 + ks], xl[ks], acc[cf], 0, 0, 0);
            }
        // acc[cf][i] = dist(code cbase+cf*16+kg*4+i, row)
        float m = fminf(fminf(fminf(acc[0][0], acc[0][1]), fminf(acc[0][2], acc[0][3])),
                        fminf(fminf(acc[1][0], acc[1][1]), fminf(acc[1][2], acc[1][3])));
        m = fminf(m, __shfl_xor(m, 16));
        m = fminf(m, __shfl_xor(m, 32));  // min over this tile's 32 codes for `row`
        // append only when the tile approaches the running min (order-free
        // superset proof: approx(w) <= rm + 2e < rm + MARGIN at winner's tile)
        if (__any(m < rm + MARGIN)) {
            const float thr = fminf(rm, m) + MARGIN;
#pragma unroll
            for (int cf = 0; cf < 2; ++cf)
#pragma unroll
                for (int i = 0; i < 4; ++i) {
                    if (acc[cf][i] < thr) {
                        int p = atomicAdd(&ccnt, 1);
                        if (p < LCAP)
                            clist[p] = (unsigned)((row << 10)
                                                  | (cbase + cf * 16 + kg * 4 + i));
                    }
                }
        }
        rm = fminf(rm, m);
    };

    // ---- barrier-free K-loop: 16 tiles, register double-buffer ----
    bfrag cur[8], nxt[8];
    load8(cur, 0);
#pragma unroll 1
    for (int t = 0; t < 16; t += 2) {
        load8(nxt, t + 1);           // in flight under compute(cur)
        compute(cur, t);
        if (t + 2 < 16) load8(cur, t + 2);  // in flight under compute(nxt)
        compute(nxt, t + 1);
    }

    __syncthreads();  // all appends visible

    // ---- exact fp32 recheck; packed LDS atomicMin keeps lowest idx on ties ----
    const int nc = (ccnt > LCAP) ? LCAP : ccnt;
    for (int b = wv * 4 + kg; b < nc; b += 16) {  // one candidate per 16-lane group
        const unsigned e = clist[b];
        const int crow = e >> 10, code = e & 1023;
        const float4* xr4 = (const float4*)(x + (size_t)(row0 + crow) * D + la * 8);
        const float4* cr4 = (const float4*)(cb + (size_t)code * D + la * 8);
        float4 a0 = xr4[0], a1 = xr4[1], b0 = cr4[0], b1 = cr4[1];
        float s = a0.x * b0.x;
        s = fmaf(a0.y, b0.y, s); s = fmaf(a0.z, b0.z, s); s = fmaf(a0.w, b0.w, s);
        s = fmaf(a1.x, b1.x, s); s = fmaf(a1.y, b1.y, s);
        s = fmaf(a1.z, b1.z, s); s = fmaf(a1.w, b1.w, s);
#pragma unroll
        for (int off = 1; off <= 8; off <<= 1) s += __shfl_xor(s, off);
        const float dist = fmaf(-2.f, s, cns[code]);
        if (la == 0)
            atomicMin(&win[crow],
                      ((unsigned long long)fenc(dist) << 32) | (unsigned)code);
    }
    __syncthreads();

    // ---- gather: out[row] = cb[winner] (coalesced float4) ----
    {
        const int r = tid >> 3, q = tid & 7;  // 32 rows x 8 chunks of 16 floats
        const int idx = (int)(win[r] & 0xFFFFFFFFull);
        const float4* cs = (const float4*)(cb + (size_t)idx * D + q * 16);
        float4* od = (float4*)(out + (size_t)(row0 + r) * D + q * 16);
#pragma unroll
        for (int i = 0; i < 4; ++i) od[i] = cs[i];
    }
}

extern "C" void kernel_launch(void* const* d_in, const int* in_sizes, int n_in,
                              void* d_out, int out_size, void* d_ws, size_t ws_size,
                              hipStream_t stream) {
    const float* x = (const float*)d_in[0];
    const float* cb = (const float*)d_in[1];
    float* out = (float*)d_out;
    const int N = in_sizes[0] / D;   // 32768
    const int K = in_sizes[1] / D;   // 1024

    float* cnorm = (float*)d_ws;                   // 4 KB
    short* cbh = (short*)((char*)d_ws + 4096);     // 256 KB bf16 fragments

    hipLaunchKernelGGL(prep_kernel, dim3(K * 16 / 256), dim3(256), 0, stream,
                       cb, cnorm, cbh, K);
    hipLaunchKernelGGL(vq_mfma, dim3(N / BR), dim3(NTH), 0, stream,
                       x, cb, cbh, cnorm, out, N, K);
}